// Round 5
// baseline (147.974 us; speedup 1.0000x reference)
//
#include <hip/hip_runtime.h>

// KMeans soft-assignment via bf16 hi/lo split MFMA (3 passes), fused softmax.
// logits = (2*x.c - ||c||^2)/T, T=0.1; ||x||^2 cancels in softmax.
// R15 == R14 resubmit (bench infra failed twice; no kernel signal).
// R14: DEEP ILP, not TLP. R10-R13 showed: reg-bound at 2 waves/SIMD always
// (64-reg alloc granularity defeats small-block occupancy plays), and the
// R12 B-pipeline (2-tile groups, ~58cyc cover) exposes ~300cyc L2 latency
// per fragment pair -> 19% MfmaUtil. New wave tile 64x64 (acc[4][4]=64):
// B per chunk = 8 loads = 32 regs -> WHOLE next chunk double-buffered in
// registers, issued one full chunk early (cover = 48 MFMA + A-convert
// ~450cyc > L2 latency). A raw issued one chunk ahead into reused regs.
// K-loop fully unrolled (static buffer indices), no barriers, no LDS.
// Block = 8 waves x same 64 rows, disjoint 64-col slices (BM=64, grid=512):
// halves block-level B L2 traffic; A-convert duplicated 8x across waves
// (~9us chip VALU, hides under MFMA pipe). Accumulation order per element
// unchanged vs R12 -> absmax unchanged.
// x: [32768,256] f32, c: [512,256] f32, out: [32768,512] f32
#define NROWS 32768
#define KC 512
#define DDIM 256
#define BM 64
#define BK 32
#define KCH (DDIM / BK)        // 8 k-chunks

typedef __attribute__((ext_vector_type(8))) short bf16x8;
typedef __attribute__((ext_vector_type(4))) float f32x4;

union U8 { unsigned short u[8]; bf16x8 v; };

__device__ __forceinline__ unsigned short f2bf(float f) {   // RNE f32->bf16
    union { float f; unsigned int u; } a; a.f = f;
    unsigned int r = a.u + 0x7fffu + ((a.u >> 16) & 1u);
    return (unsigned short)(r >> 16);
}
__device__ __forceinline__ float bf2f(unsigned short h) {
    union { unsigned int u; float f; } a; a.u = ((unsigned int)h) << 16;
    return a.f;
}

// ---- prep: c -> fragment-major bf16 hi/lo + csq10 ----
// Fragment (ks, t) = B-operand for k-chunk ks, 16-col tile t, stored as
// 64 lanes x 8 ushorts contiguous (1 KB): lane l = octet for col (t*16+(l&15)),
// k = ks*32 + (l>>4)*8 .. +7.  Main-loop load: base + lane*16B, coalesced.
__global__ __launch_bounds__(64) void prep_c(const float* __restrict__ c,
                                             unsigned short* __restrict__ bhi,
                                             unsigned short* __restrict__ blo,
                                             float* __restrict__ csq10) {
    const int n = blockIdx.x, lane = threadIdx.x;
    const int d0 = lane * 4;
    float4 v = ((const float4*)(c + (size_t)n * DDIM))[lane];
    float vv[4] = {v.x, v.y, v.z, v.w};
    unsigned short hh[4], ll[4];
    float ssq = 0.f;
    #pragma unroll
    for (int i = 0; i < 4; ++i) {
        ssq += vv[i] * vv[i];
        hh[i] = f2bf(vv[i]);
        ll[i] = f2bf(vv[i] - bf2f(hh[i]));
    }
    #pragma unroll
    for (int off = 32; off; off >>= 1) ssq += __shfl_xor(ssq, off);
    if (lane == 0) csq10[n] = 10.f * ssq;
    const int ks = d0 >> 5;            // k-chunk
    const int q  = (d0 >> 3) & 3;      // k-octet within chunk
    const int t  = n >> 4, cc = n & 15;
    const size_t dst = ((size_t)(ks * 32 + t) * 64 + (q * 16 + cc)) * 8 + (d0 & 7);
    *(ushort4*)(bhi + dst) = make_ushort4(hh[0], hh[1], hh[2], hh[3]);
    *(ushort4*)(blo + dst) = make_ushort4(ll[0], ll[1], ll[2], ll[3]);
}

// ---- main: 512 blocks x 512 threads (8 waves = 8 N-slices of 64 cols) ----
__global__ __launch_bounds__(512, 2) void kmeans_mfma(
    const float* __restrict__ x, const unsigned short* __restrict__ bhi,
    const unsigned short* __restrict__ blo, const float* __restrict__ csq10,
    float* __restrict__ out) {
    __shared__ __align__(16) float lbuf[16 * 516];   // 33 KB (epilogue only)
    __shared__ float red[2][8][BM];                  // 4 KB

    const int tid  = threadIdx.x;
    const int wn   = tid >> 6, lane = tid & 63;      // wave = 64-col slice
    const int cc   = lane & 15, q = lane >> 4;
    const int row0 = blockIdx.x * BM;

    f32x4 acc[4][4];
    #pragma unroll
    for (int mt = 0; mt < 4; ++mt)
        #pragma unroll
        for (int tt = 0; tt < 4; ++tt) acc[mt][tt] = (f32x4){0.f, 0.f, 0.f, 0.f};

    // A: lane owns rows (row0 + mt*16 + cc), k-octet q*8 within each chunk
    const float* xA0 = x + (size_t)(row0 + cc) * DDIM + q * 8;
    // B: this wave's tiles T = wn*4 + tt; fragment (ks,T) at (ks*32+T)*512 ush
    const unsigned short* bhp = bhi + ((size_t)(wn * 4) << 9) + lane * 8;
    const unsigned short* blp = blo + ((size_t)(wn * 4) << 9) + lane * 8;

    float4 ra[8];                      // raw A, chunk-ahead, regs reused
    bf16x8 pbh[2][4], pbl[2][4];       // whole-chunk B double buffer

    // ---- prologue: issue A(0) and B(0) ----
    #pragma unroll
    for (int mt = 0; mt < 4; ++mt) {
        ra[2 * mt]     = *(const float4*)(xA0 + (size_t)mt * 16 * DDIM);
        ra[2 * mt + 1] = *(const float4*)(xA0 + (size_t)mt * 16 * DDIM + 4);
    }
    #pragma unroll
    for (int tt = 0; tt < 4; ++tt) {
        pbh[0][tt] = *(const bf16x8*)(bhp + tt * 512);
        pbl[0][tt] = *(const bf16x8*)(blp + tt * 512);
    }

    #pragma unroll
    for (int ks = 0; ks < KCH; ++ks) {            // fully unrolled: static idx
        const int par = ks & 1, nxt = par ^ 1;
        // convert current A raw -> hi/lo fragments (frees ra for reuse)
        bf16x8 ah[4], al[4];
        #pragma unroll
        for (int mt = 0; mt < 4; ++mt) {
            float v[8] = {ra[2 * mt].x, ra[2 * mt].y, ra[2 * mt].z, ra[2 * mt].w,
                          ra[2 * mt + 1].x, ra[2 * mt + 1].y, ra[2 * mt + 1].z,
                          ra[2 * mt + 1].w};
            U8 H, L;
            #pragma unroll
            for (int e = 0; e < 8; ++e) {
                H.u[e] = f2bf(v[e]);
                L.u[e] = f2bf(v[e] - bf2f(H.u[e]));
            }
            ah[mt] = H.v; al[mt] = L.v;
        }
        if (ks < KCH - 1) {
            // issue next chunk's A (HBM) and B (L2) now; consumed next chunk
            const int kn = (ks + 1) * BK;
            #pragma unroll
            for (int mt = 0; mt < 4; ++mt) {
                ra[2 * mt]     = *(const float4*)(xA0 + (size_t)mt * 16 * DDIM + kn);
                ra[2 * mt + 1] = *(const float4*)(xA0 + (size_t)mt * 16 * DDIM + kn + 4);
            }
            #pragma unroll
            for (int tt = 0; tt < 4; ++tt) {
                pbh[nxt][tt] = *(const bf16x8*)(bhp + ((ks + 1) * 32 + tt) * 512);
                pbl[nxt][tt] = *(const bf16x8*)(blp + ((ks + 1) * 32 + tt) * 512);
            }
        }
        // MFMA phase on current buffers. Per-element order p0=ah*bh, p1=ah*bl,
        // p2=al*bh (bit-identical to R12); chain gap = 16 instrs.
        #pragma unroll
        for (int p = 0; p < 3; ++p)
            #pragma unroll
            for (int tt = 0; tt < 4; ++tt) {
                const bf16x8 b = (p == 1) ? pbl[par][tt] : pbh[par][tt];
                #pragma unroll
                for (int mt = 0; mt < 4; ++mt) {
                    const bf16x8 a = (p == 2) ? al[mt] : ah[mt];
                    acc[mt][tt] = __builtin_amdgcn_mfma_f32_16x16x32_bf16(a, b, acc[mt][tt], 0, 0, 0);
                }
            }
    }

    // ---- softmax stats: reduce over tt, cc-lanes, then 8 wn slices via LDS ----
    float csqv[4];
    #pragma unroll
    for (int tt = 0; tt < 4; ++tt) csqv[tt] = csq10[wn * 64 + tt * 16 + cc];
    const int rb = q * 4;   // row-in-tile base; + mt*16 + g
    float M[4][4], I[4][4];
    #pragma unroll
    for (int mt = 0; mt < 4; ++mt)
        #pragma unroll
        for (int g = 0; g < 4; ++g) {
            float pm = -1e30f;
            #pragma unroll
            for (int tt = 0; tt < 4; ++tt)
                pm = fmaxf(pm, 20.f * acc[mt][tt][g] - csqv[tt]);
            #pragma unroll
            for (int off = 1; off < 16; off <<= 1) pm = fmaxf(pm, __shfl_xor(pm, off));
            if (cc == 0) red[0][wn][mt * 16 + rb + g] = pm;
        }
    __syncthreads();
    #pragma unroll
    for (int mt = 0; mt < 4; ++mt)
        #pragma unroll
        for (int g = 0; g < 4; ++g) {
            const int ri = mt * 16 + rb + g;
            float m = fmaxf(fmaxf(fmaxf(red[0][0][ri], red[0][1][ri]),
                                  fmaxf(red[0][2][ri], red[0][3][ri])),
                            fmaxf(fmaxf(red[0][4][ri], red[0][5][ri]),
                                  fmaxf(red[0][6][ri], red[0][7][ri])));
            M[mt][g] = m;
            float ps = 0.f;
            #pragma unroll
            for (int tt = 0; tt < 4; ++tt)
                ps += __expf(20.f * acc[mt][tt][g] - csqv[tt] - m);
            #pragma unroll
            for (int off = 1; off < 16; off <<= 1) ps += __shfl_xor(ps, off);
            if (cc == 0) red[1][wn][ri] = ps;
        }
    __syncthreads();
    #pragma unroll
    for (int mt = 0; mt < 4; ++mt)
        #pragma unroll
        for (int g = 0; g < 4; ++g) {
            const int ri = mt * 16 + rb + g;
            I[mt][g] = 1.f / (((red[1][0][ri] + red[1][1][ri]) +
                               (red[1][2][ri] + red[1][3][ri])) +
                              ((red[1][4][ri] + red[1][5][ri]) +
                               (red[1][6][ri] + red[1][7][ri])));
        }

    // ---- transpose epilogue: 4 passes of 16 rows; all 8 waves write each pass ----
    #pragma unroll
    for (int p = 0; p < 4; ++p) {
        #pragma unroll
        for (int g = 0; g < 4; ++g) {
            const int   lr = rb + g;
            const float mg = M[p][g], ig = I[p][g];
            #pragma unroll
            for (int tt = 0; tt < 4; ++tt)
                lbuf[lr * 516 + wn * 64 + tt * 16 + cc] =
                    __expf(20.f * acc[p][tt][g] - csqv[tt] - mg) * ig;
        }
        __syncthreads();
        #pragma unroll
        for (int j = 0; j < 4; ++j) {
            const int f    = j * 512 + tid;     // 0..2047 float4 slots
            const int lrow = f >> 7;            // 0..15
            const int c4   = f & 127;
            float4    v    = *(const float4*)&lbuf[lrow * 516 + c4 * 4];
            *(float4*)(out + (size_t)(row0 + p * 16 + lrow) * KC + c4 * 4) = v;
        }
        __syncthreads();
    }
}

extern "C" void kernel_launch(void* const* d_in, const int* in_sizes, int n_in,
                              void* d_out, int out_size, void* d_ws, size_t ws_size,
                              hipStream_t stream) {
    const float* x   = (const float*)d_in[0];
    const float* c   = (const float*)d_in[1];
    float*       out = (float*)d_out;

    unsigned short* bhi   = (unsigned short*)d_ws;                    // 256 KB
    unsigned short* blo   = bhi + (size_t)KCH * KC * BK;              // 256 KB
    float*          csq10 = (float*)(blo + (size_t)KCH * KC * BK);    // 2 KB

    prep_c<<<KC, 64, 0, stream>>>(c, bhi, blo, csq10);
    kmeans_mfma<<<NROWS / BM, 512, 0, stream>>>(x, bhi, blo, csq10, out);
}

// Round 6
// 126.194 us; speedup vs baseline: 1.1726x; 1.1726x over previous
//
#include <hip/hip_runtime.h>

// KMeans soft-assignment via bf16 hi/lo split MFMA (3 passes), fused softmax.
// logits = (2*x.c - ||c||^2)/T, T=0.1; ||x||^2 cancels in softmax.
// R16: 2 blocks/CU (proven reachable in R11: 67.5KB LDS, 128-reg cap) with
// the DMA *always shadowed*. Per chunk, two table-phases (Bh then Bl; per-
// element pass order h*h, l*h, h*l -- f32 reorder noise << tol). 2x32KB LDS
// ring double-buffers single tables: DMA for table i+1 issued at top of
// phase i -> lands under >=1200cyc of MFMA, drained only by the phase
// barrier (m97 lesson: barrier vmcnt(0) is free if the DMA shadow covers
// it; R11's fault was a shadow-less 2nd barrier). B never touches VGPRs
// (global_load_lds), LDS->reg reads ride lgkmcnt (decoupled from vmcnt --
// R12's single-counter serialization is gone). A(ks+1) issued in Bl-phase
// (oldest in queue -> its wait never drains younger DMAs). Geometry = R11:
// BM=64, 8 waves = 2wm x 4wn, wave 32x128, acc[2][8]=64 AGPR; arch diet
// ~60 regs -> fits launch_bounds(512,4) 128-reg cap -> 2 blocks/CU.
// x: [32768,256] f32, c: [512,256] f32, out: [32768,512] f32
#define NROWS 32768
#define KC 512
#define DDIM 256
#define BM 64
#define BK 32
#define KCH (DDIM / BK)        // 8 k-chunks
#define CHUNK_USH (KC * BK)    // 16384 ushorts = 32 KB per chunk table

typedef __attribute__((ext_vector_type(8))) short bf16x8;
typedef __attribute__((ext_vector_type(4))) float f32x4;

union U8 { unsigned short u[8]; bf16x8 v; };

__device__ __forceinline__ unsigned short f2bf(float f) {   // RNE f32->bf16
    union { float f; unsigned int u; } a; a.f = f;
    unsigned int r = a.u + 0x7fffu + ((a.u >> 16) & 1u);
    return (unsigned short)(r >> 16);
}
__device__ __forceinline__ float bf2f(unsigned short h) {
    union { unsigned int u; float f; } a; a.u = ((unsigned int)h) << 16;
    return a.f;
}
// async global->LDS, 16B/lane; LDS dst must be wave-uniform base + lane*16
__device__ __forceinline__ void ld16(const void* g, void* l) {
    __builtin_amdgcn_global_load_lds(
        (const __attribute__((address_space(1))) unsigned int*)g,
        (__attribute__((address_space(3))) unsigned int*)l, 16, 0, 0);
}

// ---- prep: c -> fragment-major bf16 hi/lo + csq10 (lane-linear, no swizzle) ----
// Fragment (ks, t) = B-operand for k-chunk ks, 16-col tile t, stored as
// 64 lanes x 8 ushorts contiguous (1 KB): lane l = octet for col (t*16+(l&15)),
// k = ks*32 + (l>>4)*8 .. +7.  DMA/ds_read: base + lane*16B, conflict-free.
__global__ __launch_bounds__(64) void prep_c(const float* __restrict__ c,
                                             unsigned short* __restrict__ bhi,
                                             unsigned short* __restrict__ blo,
                                             float* __restrict__ csq10) {
    const int n = blockIdx.x, lane = threadIdx.x;
    const int d0 = lane * 4;
    float4 v = ((const float4*)(c + (size_t)n * DDIM))[lane];
    float vv[4] = {v.x, v.y, v.z, v.w};
    unsigned short hh[4], ll[4];
    float ssq = 0.f;
    #pragma unroll
    for (int i = 0; i < 4; ++i) {
        ssq += vv[i] * vv[i];
        hh[i] = f2bf(vv[i]);
        ll[i] = f2bf(vv[i] - bf2f(hh[i]));
    }
    #pragma unroll
    for (int off = 32; off; off >>= 1) ssq += __shfl_xor(ssq, off);
    if (lane == 0) csq10[n] = 10.f * ssq;
    const int ks = d0 >> 5;            // k-chunk
    const int q  = (d0 >> 3) & 3;      // k-octet within chunk
    const int t  = n >> 4, cc = n & 15;
    const size_t dst = ((size_t)ks * CHUNK_USH) + ((size_t)t * 64 + (q * 16 + cc)) * 8 + (d0 & 7);
    *(ushort4*)(bhi + dst) = make_ushort4(hh[0], hh[1], hh[2], hh[3]);
    *(ushort4*)(blo + dst) = make_ushort4(ll[0], ll[1], ll[2], ll[3]);
}

// ---- main: 512 blocks x 512 threads (8 waves = 2 M-groups x 4 N-quarters) ----
union SmemU {
    unsigned short tab[2][CHUNK_USH];   // 2-deep ring of 32 KB tables (64 KB)
    float lbuf[16 * 516];               // 33 KB overlay (epilogue only)
};

__global__ __launch_bounds__(512, 4) void kmeans_mfma(
    const float* __restrict__ x, const unsigned short* __restrict__ bhi,
    const unsigned short* __restrict__ blo, const float* __restrict__ csq10,
    float* __restrict__ out) {
    __shared__ __align__(16) SmemU sm;
    __shared__ float red[2][4][BM];   // 2 KB

    const int tid  = threadIdx.x;
    const int w    = tid >> 6, lane = tid & 63;
    const int wm   = w >> 2, wn = w & 3;
    const int cc   = lane & 15, q = lane >> 4;
    const int row0 = blockIdx.x * BM;

    f32x4 acc[2][8];
    #pragma unroll
    for (int mt = 0; mt < 2; ++mt)
        #pragma unroll
        for (int t = 0; t < 8; ++t) acc[mt][t] = (f32x4){0.f, 0.f, 0.f, 0.f};

    // A: lane owns rows (row0 + wm*32 + mt*16 + cc), k-octet q*8 per chunk
    const float* xA0 = x + (size_t)(row0 + wm * 32 + cc) * DDIM + q * 8;
    const float* xA1 = xA0 + (size_t)16 * DDIM;
    // DMA slot: wave w stages table fragments w*4+j (j=0..3), 1 KB each
    const int dmaOff = w * 4 * 512;          // ushort offset within a table
    // ds_read base for this wave's tiles T = wn*8 + t
    const int rdOff = (wn * 8) * 512 + lane * 8;

    // ---- prologue: A(0) raw; DMA Bh(0) -> tab[0] ----
    float4 c00 = *(const float4*)xA0;
    float4 c01 = *(const float4*)(xA0 + 4);
    float4 c10 = *(const float4*)xA1;
    float4 c11 = *(const float4*)(xA1 + 4);
    #pragma unroll
    for (int j = 0; j < 4; ++j) {
        const int o = dmaOff + j * 512;
        ld16(bhi + o + lane * 8, &sm.tab[0][o]);
    }
    __syncthreads();   // Bh(0) resident

    int cur = 0;
    for (int ks = 0; ks < KCH; ++ks) {
        // ======== phase H: tab[cur] = Bh(ks) ========
        // issue DMA Bl(ks) -> tab[cur^1]; lands under this phase's MFMAs
        {
            const unsigned short* src = blo + (size_t)ks * CHUNK_USH;
            #pragma unroll
            for (int j = 0; j < 4; ++j) {
                const int o = dmaOff + j * 512;
                ld16(src + o + lane * 8, &sm.tab[cur ^ 1][o]);
            }
        }
        // convert A(ks) (raw regs loaded one phase ago; oldest in vmcnt queue)
        bf16x8 ah[2], al[2];
        {
            float v0[8] = {c00.x, c00.y, c00.z, c00.w, c01.x, c01.y, c01.z, c01.w};
            float v1[8] = {c10.x, c10.y, c10.z, c10.w, c11.x, c11.y, c11.z, c11.w};
            U8 H0, L0, H1, L1;
            #pragma unroll
            for (int e = 0; e < 8; ++e) {
                H0.u[e] = f2bf(v0[e]); L0.u[e] = f2bf(v0[e] - bf2f(H0.u[e]));
                H1.u[e] = f2bf(v1[e]); L1.u[e] = f2bf(v1[e] - bf2f(H1.u[e]));
            }
            ah[0] = H0.v; al[0] = L0.v; ah[1] = H1.v; al[1] = L1.v;
        }
        // 32 MFMAs: passes h*h and l*h from the Bh table
        #pragma unroll
        for (int t = 0; t < 8; ++t) {
            bf16x8 bh = *(const bf16x8*)&sm.tab[cur][rdOff + t * 512];
            acc[0][t] = __builtin_amdgcn_mfma_f32_16x16x32_bf16(ah[0], bh, acc[0][t], 0, 0, 0);
            acc[1][t] = __builtin_amdgcn_mfma_f32_16x16x32_bf16(ah[1], bh, acc[1][t], 0, 0, 0);
            acc[0][t] = __builtin_amdgcn_mfma_f32_16x16x32_bf16(al[0], bh, acc[0][t], 0, 0, 0);
            acc[1][t] = __builtin_amdgcn_mfma_f32_16x16x32_bf16(al[1], bh, acc[1][t], 0, 0, 0);
        }
        __syncthreads();   // Bl(ks) DMA drained under the 32-MFMA shadow
        cur ^= 1;

        // ======== phase L: tab[cur] = Bl(ks) ========
        if (ks < KCH - 1) {
            // A(ks+1) first (oldest -> its wait never drains younger DMAs)
            const int kn = (ks + 1) * BK;
            c00 = *(const float4*)(xA0 + kn);
            c01 = *(const float4*)(xA0 + kn + 4);
            c10 = *(const float4*)(xA1 + kn);
            c11 = *(const float4*)(xA1 + kn + 4);
            // then DMA Bh(ks+1) -> tab[cur^1]
            const unsigned short* src = bhi + (size_t)(ks + 1) * CHUNK_USH;
            #pragma unroll
            for (int j = 0; j < 4; ++j) {
                const int o = dmaOff + j * 512;
                ld16(src + o + lane * 8, &sm.tab[cur ^ 1][o]);
            }
        }
        // 16 MFMAs: pass h*l from the Bl table
        #pragma unroll
        for (int t = 0; t < 8; ++t) {
            bf16x8 bl = *(const bf16x8*)&sm.tab[cur][rdOff + t * 512];
            acc[0][t] = __builtin_amdgcn_mfma_f32_16x16x32_bf16(ah[0], bl, acc[0][t], 0, 0, 0);
            acc[1][t] = __builtin_amdgcn_mfma_f32_16x16x32_bf16(ah[1], bl, acc[1][t], 0, 0, 0);
        }
        __syncthreads();   // Bh(ks+1) DMA drained under the 16-MFMA shadow
        cur ^= 1;
    }

    // ---- softmax stats: reduce over t, then cc-lanes, then 4 wn groups ----
    float csqv[8];
    #pragma unroll
    for (int t = 0; t < 8; ++t) csqv[t] = csq10[wn * 128 + t * 16 + cc];
    const int rb = wm * 32 + q * 4;   // + mt*16 + g
    float M[2][4], I[2][4];
    #pragma unroll
    for (int mt = 0; mt < 2; ++mt)
        #pragma unroll
        for (int g = 0; g < 4; ++g) {
            float pm = -1e30f;
            #pragma unroll
            for (int t = 0; t < 8; ++t) pm = fmaxf(pm, 20.f * acc[mt][t][g] - csqv[t]);
            #pragma unroll
            for (int off = 1; off < 16; off <<= 1) pm = fmaxf(pm, __shfl_xor(pm, off));
            if (cc == 0) red[0][wn][rb + mt * 16 + g] = pm;
        }
    __syncthreads();
    #pragma unroll
    for (int mt = 0; mt < 2; ++mt)
        #pragma unroll
        for (int g = 0; g < 4; ++g) {
            const int ri = rb + mt * 16 + g;
            const float m = fmaxf(fmaxf(red[0][0][ri], red[0][1][ri]),
                                  fmaxf(red[0][2][ri], red[0][3][ri]));
            M[mt][g] = m;
            float ps = 0.f;
            #pragma unroll
            for (int t = 0; t < 8; ++t) ps += __expf(20.f * acc[mt][t][g] - csqv[t] - m);
            #pragma unroll
            for (int off = 1; off < 16; off <<= 1) ps += __shfl_xor(ps, off);
            if (cc == 0) red[1][wn][ri] = ps;
        }
    __syncthreads();
    #pragma unroll
    for (int mt = 0; mt < 2; ++mt)
        #pragma unroll
        for (int g = 0; g < 4; ++g) {
            const int ri = rb + mt * 16 + g;
            I[mt][g] = 1.f / (red[1][0][ri] + red[1][1][ri] +
                              red[1][2][ri] + red[1][3][ri]);
        }

    // ---- transpose epilogue: 4 passes of 16 rows through lbuf, dense stores ----
    #pragma unroll
    for (int p = 0; p < 4; ++p) {
        if (wm == (p >> 1)) {
            const int mt = p & 1;
            #pragma unroll
            for (int g = 0; g < 4; ++g) {
                const int   lr = q * 4 + g;
                const float mg = M[mt][g], ig = I[mt][g];
                #pragma unroll
                for (int t = 0; t < 8; ++t)
                    sm.lbuf[lr * 516 + wn * 128 + t * 16 + cc] =
                        __expf(20.f * acc[mt][t][g] - csqv[t] - mg) * ig;
            }
        }
        __syncthreads();
        #pragma unroll
        for (int j = 0; j < 4; ++j) {
            const int f    = j * 512 + tid;     // 0..2047 float4 slots
            const int lrow = f >> 7;            // 0..15
            const int c4   = f & 127;
            float4    v    = *(const float4*)&sm.lbuf[lrow * 516 + c4 * 4];
            *(float4*)(out + (size_t)(row0 + p * 16 + lrow) * KC + c4 * 4) = v;
        }
        __syncthreads();
    }
}

extern "C" void kernel_launch(void* const* d_in, const int* in_sizes, int n_in,
                              void* d_out, int out_size, void* d_ws, size_t ws_size,
                              hipStream_t stream) {
    const float* x   = (const float*)d_in[0];
    const float* c   = (const float*)d_in[1];
    float*       out = (float*)d_out;

    unsigned short* bhi   = (unsigned short*)d_ws;                    // 256 KB
    unsigned short* blo   = bhi + (size_t)KCH * CHUNK_USH;            // 256 KB
    float*          csq10 = (float*)(blo + (size_t)KCH * CHUNK_USH);  // 2 KB

    prep_c<<<KC, 64, 0, stream>>>(c, bhi, blo, csq10);
    kmeans_mfma<<<NROWS / BM, 512, 0, stream>>>(x, bhi, blo, csq10, out);
}

// Round 7
// 117.610 us; speedup vs baseline: 1.2582x; 1.0730x over previous
//
#include <hip/hip_runtime.h>

// KMeans soft-assignment via bf16 hi/lo split MFMA (3 passes), fused softmax.
// logits = (2*x.c - ||c||^2)/T, T=0.1; ||x||^2 cancels in softmax.
// R17: R10 (best, 48us) with the K-loop sync rewritten to T3/T4 counted
// vmcnt (the one untried proven lever; m218: counted-vs-drain0 +38-73%).
// R10-R16 summary: occupancy 17->35% changed nothing; every variant drains
// vmcnt(0) at each barrier (__syncthreads) -> all are m97-structure kernels.
// New schedule per chunk: convert A(ks) [compiler waits vmcnt(8), DMA(ks)
// stays in flight] -> issue A(ks+1) -> asm vmcnt(4) [DMA(ks) done, A(ks+1)
// in flight] -> raw s_barrier -> issue DMA(ks+1) into other slot [safe
// post-barrier: prior readers of that slot consumed their ds_reads before
// the barrier] -> 16 ds_read + 48 MFMA. Nothing drains to 0 except the
// peeled last chunk. sched_barrier(0) pins asm waits (rule #18).
// Geometry/math/layout identical to R10 -> pure schedule A/B, absmax same.
// x: [32768,256] f32, c: [512,256] f32, out: [32768,512] f32
#define NROWS 32768
#define KC 512
#define DDIM 256
#define BM 128
#define BK 32
#define KCH (DDIM / BK)        // 8 k-chunks
#define CHUNK_USH (KC * BK)    // 16384 ushorts = 32 KB per chunk table

typedef __attribute__((ext_vector_type(8))) short bf16x8;
typedef __attribute__((ext_vector_type(4))) float f32x4;

union U8 { unsigned short u[8]; bf16x8 v; };

__device__ __forceinline__ unsigned short f2bf(float f) {   // RNE f32->bf16
    union { float f; unsigned int u; } a; a.f = f;
    unsigned int r = a.u + 0x7fffu + ((a.u >> 16) & 1u);
    return (unsigned short)(r >> 16);
}
__device__ __forceinline__ float bf2f(unsigned short h) {
    union { unsigned int u; float f; } a; a.u = ((unsigned int)h) << 16;
    return a.f;
}
// async global->LDS, 16B/lane; LDS dst must be wave-uniform base + lane*16
__device__ __forceinline__ void ld16(const void* g, void* l) {
    __builtin_amdgcn_global_load_lds(
        (const __attribute__((address_space(1))) unsigned int*)g,
        (__attribute__((address_space(3))) unsigned int*)l, 16, 0, 0);
}

// ---- prep: c -> chunk-major, LDS-swizzle-baked bf16 hi/lo + csq10 ----
// octet (col n, quad q) at chunk offset (n*4 + (q ^ ((n>>1)&3)))*8 ushorts
__global__ __launch_bounds__(64) void prep_c(const float* __restrict__ c,
                                             unsigned short* __restrict__ bhi,
                                             unsigned short* __restrict__ blo,
                                             float* __restrict__ csq10) {
    const int n = blockIdx.x, lane = threadIdx.x;
    const int d0 = lane * 4;
    float4 v = ((const float4*)(c + (size_t)n * DDIM))[lane];
    float vv[4] = {v.x, v.y, v.z, v.w};
    unsigned short hh[4], ll[4];
    float ssq = 0.f;
    #pragma unroll
    for (int i = 0; i < 4; ++i) {
        ssq += vv[i] * vv[i];
        hh[i] = f2bf(vv[i]);
        ll[i] = f2bf(vv[i] - bf2f(hh[i]));
    }
    #pragma unroll
    for (int off = 32; off; off >>= 1) ssq += __shfl_xor(ssq, off);
    if (lane == 0) csq10[n] = 10.f * ssq;
    const int ks = d0 >> 5;
    const int q  = (d0 >> 3) & 3;
    const int s  = q ^ ((n >> 1) & 3);
    const size_t dst = (size_t)ks * CHUNK_USH + (n * 4 + s) * 8 + (d0 & 7);
    *(ushort4*)(bhi + dst) = make_ushort4(hh[0], hh[1], hh[2], hh[3]);
    *(ushort4*)(blo + dst) = make_ushort4(ll[0], ll[1], ll[2], ll[3]);
}

// ---- main: 256 blocks x 512 threads (8 waves = 4 M-groups x 2 N-halves) ----
union SmemU {
    struct { unsigned short Bh[2][CHUNK_USH], Bl[2][CHUNK_USH]; } k;  // 128 KB
    float lbuf[32 * 516];                                             // 66 KB overlay
};

__global__ __launch_bounds__(512, 2) void kmeans_mfma(
    const float* __restrict__ x, const unsigned short* __restrict__ bhi,
    const unsigned short* __restrict__ blo, const float* __restrict__ csq10,
    float* __restrict__ out) {
    __shared__ __align__(16) SmemU sm;
    __shared__ float red[2][2][BM];   // 2 KB

    const int tid  = threadIdx.x;
    const int w    = tid >> 6, lane = tid & 63;
    const int wm   = w >> 1, wn = w & 1;
    const int cc   = lane & 15, q = lane >> 4;
    const int row0 = blockIdx.x * BM;

    f32x4 acc[2][16];
    #pragma unroll
    for (int mt = 0; mt < 2; ++mt)
        #pragma unroll
        for (int t = 0; t < 16; ++t) acc[mt][t] = (f32x4){0.f, 0.f, 0.f, 0.f};

    // A: lane owns rows (row0 + wm*32 + mt*16 + cc), k-octet q*8 per chunk
    const float* xA0 = x + (size_t)(row0 + wm * 32 + cc) * DDIM + q * 8;
    const float* xA1 = xA0 + (size_t)16 * DDIM;
    // B fragment offset within staged chunk
    const int sF = q ^ ((cc >> 1) & 3);
    const int bF = (4 * cc + sF) * 8;       // + (wn*16+t)*512
    // DMA slots: wave w, j=0..3 -> 1 KB segment (w*4+j)*512 ushorts
    const int dmaOff = (w * 4) * 512;

    // ---- prologue: issue A(0), then DMA chunk 0 -> buf 0 (no barrier yet) ----
    float4 c00 = *(const float4*)xA0;
    float4 c01 = *(const float4*)(xA0 + 4);
    float4 c10 = *(const float4*)xA1;
    float4 c11 = *(const float4*)(xA1 + 4);
    #pragma unroll
    for (int j = 0; j < 4; ++j) {
        const int o = dmaOff + j * 512;
        ld16(bhi + o + lane * 8, &sm.k.Bh[0][o]);
        ld16(blo + o + lane * 8, &sm.k.Bl[0][o]);
    }

    #pragma unroll
    for (int ks = 0; ks < KCH; ++ks) {
        const int pp = ks & 1;
        // convert A(ks): compiler inserts a COUNTED vmcnt for these regs
        // (DMA(ks)'s 8 ops are younger -> stay in flight)
        bf16x8 ah[2], al[2];
        {
            float v0[8] = {c00.x, c00.y, c00.z, c00.w, c01.x, c01.y, c01.z, c01.w};
            float v1[8] = {c10.x, c10.y, c10.z, c10.w, c11.x, c11.y, c11.z, c11.w};
            U8 H0, L0, H1, L1;
            #pragma unroll
            for (int e = 0; e < 8; ++e) {
                H0.u[e] = f2bf(v0[e]); L0.u[e] = f2bf(v0[e] - bf2f(H0.u[e]));
                H1.u[e] = f2bf(v1[e]); L1.u[e] = f2bf(v1[e] - bf2f(H1.u[e]));
            }
            ah[0] = H0.v; al[0] = L0.v; ah[1] = H1.v; al[1] = L1.v;
        }
        // issue A(ks+1) raw (stays in flight across the barrier)
        float4 n00, n01, n10, n11;
        if (ks < KCH - 1) {
            const int kn = (ks + 1) * BK;
            n00 = *(const float4*)(xA0 + kn);
            n01 = *(const float4*)(xA0 + kn + 4);
            n10 = *(const float4*)(xA1 + kn);
            n11 = *(const float4*)(xA1 + kn + 4);
        }
        __builtin_amdgcn_sched_barrier(0);
        // counted wait: DMA(ks) complete; A(ks+1) (4 youngest) stays in flight.
        // Last chunk: nothing younger -> full drain (instant; DMA(7) had a
        // whole phase of flight).
        if (ks < KCH - 1) {
            asm volatile("s_waitcnt vmcnt(4)" ::: "memory");
        } else {
            asm volatile("s_waitcnt vmcnt(0)" ::: "memory");
        }
        __builtin_amdgcn_s_barrier();
        __builtin_amdgcn_sched_barrier(0);
        // issue DMA(ks+1) into the other slot. Safe only HERE (post-barrier):
        // chunk ks-1's readers of slot 1-pp consumed their ds_reads before
        // reaching this barrier.
        if (ks < KCH - 1) {
            const size_t cb = (size_t)(ks + 1) * CHUNK_USH;
            #pragma unroll
            for (int j = 0; j < 4; ++j) {
                const int o = dmaOff + j * 512;
                ld16(bhi + cb + o + lane * 8, &sm.k.Bh[1 - pp][o]);
                ld16(blo + cb + o + lane * 8, &sm.k.Bl[1 - pp][o]);
            }
        }
        // MFMA phase over staged buffer pp (DMA(ks+1)+A(ks+1) fly underneath)
        #pragma unroll
        for (int t = 0; t < 16; ++t) {
            const int bo = (wn * 16 + t) * 512 + bF;
            bf16x8 bh = *(const bf16x8*)&sm.k.Bh[pp][bo];
            bf16x8 bl = *(const bf16x8*)&sm.k.Bl[pp][bo];
            acc[0][t] = __builtin_amdgcn_mfma_f32_16x16x32_bf16(ah[0], bh, acc[0][t], 0, 0, 0);
            acc[1][t] = __builtin_amdgcn_mfma_f32_16x16x32_bf16(ah[1], bh, acc[1][t], 0, 0, 0);
            acc[0][t] = __builtin_amdgcn_mfma_f32_16x16x32_bf16(ah[0], bl, acc[0][t], 0, 0, 0);
            acc[1][t] = __builtin_amdgcn_mfma_f32_16x16x32_bf16(ah[1], bl, acc[1][t], 0, 0, 0);
            acc[0][t] = __builtin_amdgcn_mfma_f32_16x16x32_bf16(al[0], bh, acc[0][t], 0, 0, 0);
            acc[1][t] = __builtin_amdgcn_mfma_f32_16x16x32_bf16(al[1], bh, acc[1][t], 0, 0, 0);
        }
        c00 = n00; c01 = n01; c10 = n10; c11 = n11;
    }

    // ---- softmax stats: reduce over t, then cc-lanes, then wn pair via LDS ----
    float csqv[16];
    #pragma unroll
    for (int t = 0; t < 16; ++t) csqv[t] = csq10[wn * 256 + t * 16 + cc];
    const int rb = wm * 32 + q * 4;   // + mt*16 + g
    float M[2][4], I[2][4];
    #pragma unroll
    for (int mt = 0; mt < 2; ++mt)
        #pragma unroll
        for (int g = 0; g < 4; ++g) {
            float pm = -1e30f;
            #pragma unroll
            for (int t = 0; t < 16; ++t) pm = fmaxf(pm, 20.f * acc[mt][t][g] - csqv[t]);
            #pragma unroll
            for (int off = 1; off < 16; off <<= 1) pm = fmaxf(pm, __shfl_xor(pm, off));
            if (cc == 0) red[0][wn][rb + mt * 16 + g] = pm;
            M[mt][g] = pm;
        }
    __syncthreads();
    #pragma unroll
    for (int mt = 0; mt < 2; ++mt)
        #pragma unroll
        for (int g = 0; g < 4; ++g) {
            M[mt][g] = fmaxf(M[mt][g], red[0][1 - wn][rb + mt * 16 + g]);
            float ps = 0.f;
            #pragma unroll
            for (int t = 0; t < 16; ++t) ps += __expf(20.f * acc[mt][t][g] - csqv[t] - M[mt][g]);
            #pragma unroll
            for (int off = 1; off < 16; off <<= 1) ps += __shfl_xor(ps, off);
            if (cc == 0) red[1][wn][rb + mt * 16 + g] = ps;
        }
    __syncthreads();
    #pragma unroll
    for (int mt = 0; mt < 2; ++mt)
        #pragma unroll
        for (int g = 0; g < 4; ++g)
            I[mt][g] = 1.f / (red[1][0][rb + mt * 16 + g] + red[1][1][rb + mt * 16 + g]);

    // ---- transpose epilogue: 4 passes of 32 rows through lbuf, dense stores ----
    #pragma unroll
    for (int p = 0; p < 4; ++p) {
        if (wm == p) {
            #pragma unroll
            for (int mt = 0; mt < 2; ++mt)
                #pragma unroll
                for (int g = 0; g < 4; ++g) {
                    const int   lr = mt * 16 + q * 4 + g;
                    const float mg = M[mt][g], ig = I[mt][g];
                    #pragma unroll
                    for (int t = 0; t < 16; ++t)
                        sm.lbuf[lr * 516 + wn * 256 + t * 16 + cc] =
                            __expf(20.f * acc[mt][t][g] - csqv[t] - mg) * ig;
                }
        }
        __syncthreads();
        #pragma unroll
        for (int j = 0; j < 8; ++j) {
            const int f    = j * 512 + tid;     // 0..4095 float4 slots
            const int lrow = f >> 7;            // 0..31
            const int c4   = f & 127;
            float4    v    = *(const float4*)&sm.lbuf[lrow * 516 + c4 * 4];
            *(float4*)(out + (size_t)(row0 + p * 32 + lrow) * KC + c4 * 4) = v;
        }
        __syncthreads();
    }
}

extern "C" void kernel_launch(void* const* d_in, const int* in_sizes, int n_in,
                              void* d_out, int out_size, void* d_ws, size_t ws_size,
                              hipStream_t stream) {
    const float* x   = (const float*)d_in[0];
    const float* c   = (const float*)d_in[1];
    float*       out = (float*)d_out;

    unsigned short* bhi   = (unsigned short*)d_ws;                 // 256 KB
    unsigned short* blo   = bhi + (size_t)KCH * CHUNK_USH;         // 256 KB
    float*          csq10 = (float*)(blo + (size_t)KCH * CHUNK_USH);  // 2 KB

    prep_c<<<KC, 64, 0, stream>>>(c, bhi, blo, csq10);
    kmeans_mfma<<<NROWS / BM, 512, 0, stream>>>(x, bhi, blo, csq10, out);
}